// Round 5
// baseline (2054.230 us; speedup 1.0000x reference)
//
#include <hip/hip_runtime.h>
#include <math.h>

#define DIM 512
#define NLAYERS 6
#define KSZ 15
#define VOCAB 32000
#define BATCH 2
#define SEQ 1024
#define HIDN 1024
#define RANK 64
#define NTOK (BATCH*SEQ)
#define MIXW 0.1f

typedef unsigned short u16;
typedef _Float16 f16;
typedef _Float16 f16x8 __attribute__((ext_vector_type(8)));
typedef _Float16 f16x4 __attribute__((ext_vector_type(4)));
typedef float  f32x4  __attribute__((ext_vector_type(4)));

__device__ __forceinline__ float sigm(float x){ return 1.f/(1.f+__expf(-x)); }

__device__ __forceinline__ float wred(float v){
  #pragma unroll
  for (int o=32;o>0;o>>=1) v += __shfl_xor(v, o, 64);
  return v;
}

#define MFMA16(a,b,c) __builtin_amdgcn_mfma_f32_16x16x32_f16(a,b,c,0,0,0)

// ---------------- f32 -> f16 weight conversion ----------------
__global__ __launch_bounds__(256) void k_cvt(const float* __restrict__ s,
    f16* __restrict__ d, long n4){
  long i = (long)blockIdx.x*256 + threadIdx.x;
  if (i >= n4) return;
  float4 v = reinterpret_cast<const float4*>(s)[i];
  f16x4 o; o.x=(f16)v.x; o.y=(f16)v.y; o.z=(f16)v.z; o.w=(f16)v.w;
  reinterpret_cast<f16x4*>(d)[i] = o;
}

// ---------------- front-end ----------------
__global__ __launch_bounds__(64) void k_embnorm(const int* __restrict__ idx,
    const float* __restrict__ emb, const float* __restrict__ pos,
    const float* __restrict__ w, float* __restrict__ out){
  int row = blockIdx.x;                 // b*SEQ + t
  int t = row & (SEQ-1);
  int lane = threadIdx.x;
  long ebase = (long)idx[row]*DIM;
  long pbase = (long)t*DIM;
  float v[8]; float ss = 0.f;
  #pragma unroll
  for (int c=0;c<2;c++){
    int d = c*256 + lane*4;
    float4 e = *reinterpret_cast<const float4*>(emb + ebase + d);
    float4 p = *reinterpret_cast<const float4*>(pos + pbase + d);
    float x0 = e.x+p.x, x1 = e.y+p.y, x2 = e.z+p.z, x3 = e.w+p.w;
    v[c*4+0]=x0; v[c*4+1]=x1; v[c*4+2]=x2; v[c*4+3]=x3;
    ss += x0*x0 + x1*x1 + x2*x2 + x3*x3;
  }
  ss = wred(ss);
  float rs = rsqrtf(ss*(1.f/DIM) + 1e-6f);
  long ob = (long)row*DIM;
  #pragma unroll
  for (int c=0;c<2;c++){
    int d = c*256 + lane*4;
    float4 wv = *reinterpret_cast<const float4*>(w + d);
    float4 o;
    o.x = v[c*4+0]*rs*wv.x; o.y = v[c*4+1]*rs*wv.y;
    o.z = v[c*4+2]*rs*wv.z; o.w = v[c*4+3]*rs*wv.w;
    *reinterpret_cast<float4*>(out + ob + d) = o;
  }
}

__global__ void k_mem(const float* __restrict__ p, const float* __restrict__ gw,
                      const float* __restrict__ gb, float* __restrict__ mem){
  int i = blockIdx.x*blockDim.x + threadIdx.x;
  if (i >= BATCH*DIM) return;
  int b = i >> 9, d = i & (DIM-1);
  float acc = gb[d];
  const float* wr = gw + (long)d*DIM;
  const float* pr = p + b*DIM;
  for (int k=0;k<DIM;k+=4){
    float4 wv = *reinterpret_cast<const float4*>(wr+k);
    float4 pv = *reinterpret_cast<const float4*>(pr+k);
    acc += wv.x*pv.x + wv.y*pv.y + wv.z*pv.z + wv.w*pv.w;
  }
  mem[i] = sigm(acc);
}

__global__ void k_shift(const float* __restrict__ xn, const float* __restrict__ mem,
    const float* __restrict__ ts, float* __restrict__ out){
  int i = blockIdx.x*256 + threadIdx.x;   // over NTOK*DIM
  int d = i & (DIM-1); int row = i >> 9; int t = row & (SEQ-1); int b = row >> 10;
  float cur = xn[i];
  float v;
  if (t == 0) v = cur;
  else { float f = ts[d]; v = f*xn[i-DIM] + (1.f-f)*cur; }
  out[i] = v + mem[b*DIM + d];
}

// ---------------- norms / pid (f32 in, f16 out) ----------------
__global__ __launch_bounds__(64) void k_rms(const float* __restrict__ x,
    const float* __restrict__ w, f16* __restrict__ oh){
  int row = blockIdx.x; int lane = threadIdx.x;
  const float* xr = x + (long)row*DIM;
  float v[8]; float ss = 0.f;
  #pragma unroll
  for (int c=0;c<2;c++){
    int d = c*256 + lane*4;
    float4 f = *reinterpret_cast<const float4*>(xr + d);
    v[c*4+0]=f.x; v[c*4+1]=f.y; v[c*4+2]=f.z; v[c*4+3]=f.w;
    ss += f.x*f.x + f.y*f.y + f.z*f.z + f.w*f.w;
  }
  ss = wred(ss);
  float rs = rsqrtf(ss*(1.f/DIM) + 1e-6f);
  long ob = (long)row*DIM;
  #pragma unroll
  for (int c=0;c<2;c++){
    int d = c*256 + lane*4;
    float4 wv = *reinterpret_cast<const float4*>(w + d);
    f16x4 o;
    o.x = (f16)(v[c*4+0]*rs*wv.x); o.y = (f16)(v[c*4+1]*rs*wv.y);
    o.z = (f16)(v[c*4+2]*rs*wv.z); o.w = (f16)(v[c*4+3]*rs*wv.w);
    *reinterpret_cast<f16x4*>(oh + ob + d) = o;
  }
}

// cur_in = rmsnorm(silu(kp*C + ki*(I/i)), gn);  h1 = f16(rmsnorm(cur_in, nw))
__global__ __launch_bounds__(64) void k_pid(const float* __restrict__ C,
    const float* __restrict__ I, float inv_i,
    const float* __restrict__ kp, const float* __restrict__ ki,
    const float* __restrict__ gn, const float* __restrict__ nw,
    float* __restrict__ xin, f16* __restrict__ oh){
  int row = blockIdx.x; int lane = threadIdx.x;
  long base = (long)row*DIM;
  float u[8]; float ss = 0.f;
  #pragma unroll
  for (int c=0;c<2;c++){
    int d = c*256 + lane*4;
    float4 cv = *reinterpret_cast<const float4*>(C + base + d);
    float4 iv = *reinterpret_cast<const float4*>(I + base + d);
    float4 kpv = *reinterpret_cast<const float4*>(kp + d);
    float4 kiv = *reinterpret_cast<const float4*>(ki + d);
    float p0 = kpv.x*cv.x + kiv.x*(iv.x*inv_i);
    float p1 = kpv.y*cv.y + kiv.y*(iv.y*inv_i);
    float p2 = kpv.z*cv.z + kiv.z*(iv.z*inv_i);
    float p3 = kpv.w*cv.w + kiv.w*(iv.w*inv_i);
    float s0 = p0*sigm(p0), s1 = p1*sigm(p1), s2 = p2*sigm(p2), s3 = p3*sigm(p3);
    u[c*4+0]=s0; u[c*4+1]=s1; u[c*4+2]=s2; u[c*4+3]=s3;
    ss += s0*s0 + s1*s1 + s2*s2 + s3*s3;
  }
  ss = wred(ss);
  float rs1 = rsqrtf(ss*(1.f/DIM) + 1e-6f);
  float x2[8]; float ss2 = 0.f;
  #pragma unroll
  for (int c=0;c<2;c++){
    int d = c*256 + lane*4;
    float4 gv = *reinterpret_cast<const float4*>(gn + d);
    float y0 = u[c*4+0]*rs1*gv.x, y1 = u[c*4+1]*rs1*gv.y;
    float y2 = u[c*4+2]*rs1*gv.z, y3 = u[c*4+3]*rs1*gv.w;
    x2[c*4+0]=y0; x2[c*4+1]=y1; x2[c*4+2]=y2; x2[c*4+3]=y3;
    ss2 += y0*y0 + y1*y1 + y2*y2 + y3*y3;
    float4 o; o.x=y0; o.y=y1; o.z=y2; o.w=y3;
    *reinterpret_cast<float4*>(xin + base + d) = o;
  }
  ss2 = wred(ss2);
  float rs2 = rsqrtf(ss2*(1.f/DIM) + 1e-6f);
  #pragma unroll
  for (int c=0;c<2;c++){
    int d = c*256 + lane*4;
    float4 nv = *reinterpret_cast<const float4*>(nw + d);
    f16x4 o;
    o.x = (f16)(x2[c*4+0]*rs2*nv.x); o.y = (f16)(x2[c*4+1]*rs2*nv.y);
    o.z = (f16)(x2[c*4+2]*rs2*nv.z); o.w = (f16)(x2[c*4+3]*rs2*nv.w);
    *reinterpret_cast<f16x4*>(oh + base + d) = o;
  }
}

// ---------------- depthwise causal conv + silu ----------------
__global__ void k_conv(const f16* __restrict__ h1,
    const float* __restrict__ cw, const float* __restrict__ cb,
    f16* __restrict__ hc, int dil){
  int i = blockIdx.x*256 + threadIdx.x;   // over NTOK*DIM
  int d = i & (DIM-1); int row = i >> 9; int t = row & (SEQ-1);
  float acc = cb[d];
  const float* wr = cw + d*KSZ;
  #pragma unroll
  for (int m=0;m<KSZ;m++){
    if (t - m*dil >= 0) acc += wr[KSZ-1-m] * (float)h1[i - m*dil*DIM];
  }
  float s = acc * sigm(acc);
  hc[i] = (f16)s;
}

// ---------------- unified tiled MFMA GEMM ----------------
// C[M,N] = A[M,K] . B[N,K]^T, f16 operands, f32 accumulate. 4 waves split M.
// EPI 0: dual (B0=W1,B1=W3): OH = f16(silu(c0)*c1), ld HIDN
// EPI 1: w2: val = c0 + XIN; OF = val; I += val (ld DIM)
// EPI 2: logits: OF = c0 (ld VOCAB); 1-D grid, XCD-striped (mt = bid&7)
template<int BM,int BN,int KD,int EPI>
__global__ __launch_bounds__(256) void k_mm(
    const f16* __restrict__ A, const f16* __restrict__ B0, const f16* __restrict__ B1,
    const float* __restrict__ XIN, float* __restrict__ OF, float* __restrict__ I,
    f16* __restrict__ OH){
  constexpr int WM = BM/4, MF = WM/16, NF = BN/16;   // per-wave: WM x BN
  constexpr int ACH = BM*64/2048;       // 16B chunks per thread for A tile (BM x 64)
  constexpr int BCH = BN*64/2048;       // per B matrix
  constexpr int NMAT = (EPI==0) ? 2 : 1;
  constexpr int SAB = (BM*64 + NMAT*BN*64)*2;
  constexpr int STGB = 4*16*68*4;
  constexpr int SMEMB = SAB > STGB ? SAB : STGB;
  __shared__ char smem[SMEMB];
  f16* sA = (f16*)smem;
  f16* sB = (f16*)(smem + (size_t)BM*64*2);
  int tid = threadIdx.x;
  int lane = tid & 63, wid = tid >> 6;
  int m0, n0;
  if constexpr (EPI==2){ int bid = blockIdx.x; m0 = (bid&7)*BM; n0 = (bid>>3)*BN; }
  else { m0 = blockIdx.x*BM; n0 = blockIdx.y*BN; }

  float4 ra[ACH], rb0[BCH], rb1[(EPI==0)?BCH:1];

  auto loadT = [&](int k0){
    #pragma unroll
    for (int c=0;c<ACH;c++){
      int cc = c*256 + tid; int row = cc>>3, kp = cc&7;
      ra[c] = *reinterpret_cast<const float4*>(A + (size_t)(m0+row)*KD + k0 + kp*8);
    }
    #pragma unroll
    for (int c=0;c<BCH;c++){
      int cc = c*256 + tid; int row = cc>>3, kp = cc&7;
      rb0[c] = *reinterpret_cast<const float4*>(B0 + (size_t)(n0+row)*KD + k0 + kp*8);
      if constexpr (EPI==0)
        rb1[c] = *reinterpret_cast<const float4*>(B1 + (size_t)(n0+row)*KD + k0 + kp*8);
    }
  };

  f32x4 acc0[MF][NF] = {};
  f32x4 acc1[MF][NF] = {};

  loadT(0);
  int k0 = 0;
  while (true){
    __syncthreads();
    // swizzled LDS write: 16B slot index kp -> kp ^ (row&7)  (BK=64 f16 = 128B rows)
    #pragma unroll
    for (int c=0;c<ACH;c++){
      int cc = c*256 + tid; int row = cc>>3, kp = cc&7;
      *reinterpret_cast<float4*>(&sA[row*64 + (kp^(row&7))*8]) = ra[c];
    }
    #pragma unroll
    for (int c=0;c<BCH;c++){
      int cc = c*256 + tid; int row = cc>>3, kp = cc&7;
      *reinterpret_cast<float4*>(&sB[row*64 + (kp^(row&7))*8]) = rb0[c];
      if constexpr (EPI==0)
        *reinterpret_cast<float4*>(&sB[BN*64 + row*64 + (kp^(row&7))*8]) = rb1[c];
    }
    __syncthreads();
    int knext = k0 + 64;
    if (knext < KD) loadT(knext);   // prefetch overlaps MFMA below
    #pragma unroll
    for (int kk=0;kk<2;kk++){
      int kp0 = kk*4 + (lane>>4);   // 16B chunk 0..7 within row
      f16x8 af[MF], bf[NF], bg[(EPI==0)?NF:1];
      #pragma unroll
      for (int mf=0;mf<MF;mf++){
        int row = wid*WM + mf*16 + (lane&15);
        af[mf] = *reinterpret_cast<const f16x8*>(&sA[row*64 + (kp0^(row&7))*8]);
      }
      #pragma unroll
      for (int nf=0;nf<NF;nf++){
        int row = nf*16 + (lane&15);
        bf[nf] = *reinterpret_cast<const f16x8*>(&sB[row*64 + (kp0^(row&7))*8]);
        if constexpr (EPI==0)
          bg[nf] = *reinterpret_cast<const f16x8*>(&sB[BN*64 + row*64 + (kp0^(row&7))*8]);
      }
      #pragma unroll
      for (int mf=0;mf<MF;mf++){
        #pragma unroll
        for (int nf=0;nf<NF;nf++){
          acc0[mf][nf] = MFMA16(af[mf], bf[nf], acc0[mf][nf]);
          if constexpr (EPI==0)
            acc1[mf][nf] = MFMA16(af[mf], bg[nf], acc1[mf][nf]);
        }
      }
    }
    k0 = knext;
    if (k0 >= KD) break;
  }

  // ---- LDS-staged coalesced epilogue (wave-private staging, stride 68) ----
  __syncthreads();                       // done with sA/sB; reuse as staging
  float* stg = (float*)smem + wid*(16*68);
  int dr = (lane>>4)*4, dc = lane&15;
  #pragma unroll
  for (int mf=0;mf<MF;mf++){
    #pragma unroll
    for (int nf=0;nf<NF;nf++){
      #pragma unroll
      for (int q=0;q<4;q++){
        float v;
        if constexpr (EPI==0){
          float x1 = acc0[mf][nf][q];
          v = x1*sigm(x1)*acc1[mf][nf][q];
        } else v = acc0[mf][nf][q];
        stg[(dr+q)*68 + nf*16 + dc] = v;
      }
    }
    int gmb = m0 + wid*WM + mf*16;
    if constexpr (EPI==0){
      #pragma unroll
      for (int pass=0;pass<2;pass++){
        int r = pass*8 + (lane>>3);
        int c = 8*(lane&7);
        float4 lo = *reinterpret_cast<float4*>(&stg[r*68 + c]);
        float4 hi = *reinterpret_cast<float4*>(&stg[r*68 + c + 4]);
        f16x8 o;
        o[0]=(f16)lo.x; o[1]=(f16)lo.y; o[2]=(f16)lo.z; o[3]=(f16)lo.w;
        o[4]=(f16)hi.x; o[5]=(f16)hi.y; o[6]=(f16)hi.z; o[7]=(f16)hi.w;
        *reinterpret_cast<f16x8*>(&OH[(size_t)(gmb+r)*HIDN + n0 + c]) = o;
      }
    } else if constexpr (EPI==1){
      #pragma unroll
      for (int pass=0;pass<4;pass++){
        int r = pass*4 + (lane>>4);
        int c = 4*(lane&15);
        float4 v = *reinterpret_cast<float4*>(&stg[r*68 + c]);
        size_t o = (size_t)(gmb+r)*DIM + n0 + c;
        float4 x = *reinterpret_cast<const float4*>(&XIN[o]);
        v.x += x.x; v.y += x.y; v.z += x.z; v.w += x.w;
        *reinterpret_cast<float4*>(&OF[o]) = v;
        float4 iv = *reinterpret_cast<const float4*>(&I[o]);
        iv.x += v.x; iv.y += v.y; iv.z += v.z; iv.w += v.w;
        *reinterpret_cast<float4*>(&I[o]) = iv;
      }
    } else {
      #pragma unroll
      for (int pass=0;pass<4;pass++){
        int r = pass*4 + (lane>>4);
        int c = 4*(lane&15);
        float4 v = *reinterpret_cast<float4*>(&stg[r*68 + c]);
        *reinterpret_cast<float4*>(&OF[(size_t)(gmb+r)*VOCAB + n0 + c]) = v;
      }
    }
  }
}

// ---------------- mix: parallel scan, one wave per (b,d) column ----------------
__global__ __launch_bounds__(64) void k_mix(float* __restrict__ x){
  int col = blockIdx.x;                 // 0..BATCH*DIM-1
  int b = col >> 9, d = col & (DIM-1);
  int lane = threadIdx.x;
  long o = (long)b*SEQ*DIM + d + (long)lane*16*DIM;
  float v[16]; float s = 0.f;
  #pragma unroll
  for (int j=0;j<16;j++){ v[j] = x[o + (long)j*DIM]; s += v[j]; }
  float t = s;
  #pragma unroll
  for (int off=1; off<64; off<<=1){
    float u = __shfl_up(t, off, 64);
    if (lane >= off) t += u;
  }
  float run = t - s;   // exclusive prefix
  #pragma unroll
  for (int j=0;j<16;j++){
    run += v[j];
    int tt = lane*16 + j;
    x[o + (long)j*DIM] = v[j] + MIXW*run/(float)(tt+1);
  }
}

// ---------------- sgate (low-rank gate) ----------------
__global__ __launch_bounds__(256) void k_sgate(const float* __restrict__ xnew,
    const float* __restrict__ xold, const float* __restrict__ nw,
    const float* __restrict__ dw, const float* __restrict__ db,
    const float* __restrict__ uw, const float* __restrict__ ub,
    float* __restrict__ out){
  __shared__ float raw[DIM];
  __shared__ float xn[DIM];
  __shared__ float part[256];
  __shared__ float hb[RANK];
  int row = blockIdx.x, tid = threadIdx.x;
  long base = (long)row*DIM;
  float ss = 0.f;
  for (int d=tid; d<DIM; d+=256){ float v = xnew[base+d]; raw[d]=v; ss += v*v; }
  ss = wred(ss);
  if ((tid&63)==0) part[tid>>6] = ss;
  __syncthreads();
  float tot = part[0]+part[1]+part[2]+part[3];
  float rs = rsqrtf(tot*(1.f/DIM)+1e-6f);
  for (int d=tid; d<DIM; d+=256) xn[d] = raw[d]*rs*nw[d];
  __syncthreads();
  int rr = tid & 63, q = tid >> 6;
  float p = 0.f;
  const float* dwr = dw + (long)rr*DIM + q*128;
  const float* xq = xn + q*128;
  #pragma unroll 8
  for (int d=0; d<128; d+=4){
    float4 wv = *reinterpret_cast<const float4*>(dwr+d);
    p += xq[d]*wv.x + xq[d+1]*wv.y + xq[d+2]*wv.z + xq[d+3]*wv.w;
  }
  part[tid] = p;
  __syncthreads();
  if (tid < RANK){
    float h = part[tid] + part[64+tid] + part[128+tid] + part[192+tid] + db[tid];
    hb[tid] = h * sigm(h);
  }
  __syncthreads();
  for (int d=tid; d<DIM; d+=256){
    float a = ub[d];
    const float* ur = uw + (long)d*RANK;
    #pragma unroll
    for (int rj=0;rj<RANK;rj+=4){
      float4 uv = *reinterpret_cast<const float4*>(ur+rj);
      a += hb[rj]*uv.x + hb[rj+1]*uv.y + hb[rj+2]*uv.z + hb[rj+3]*uv.w;
    }
    float g = sigm(a);
    out[base+d] = g*raw[d] + (1.f-g)*xold[base+d];
  }
}

// ---------------- host orchestration ----------------
extern "C" void kernel_launch(void* const* d_in, const int* in_sizes, int n_in,
                              void* d_out, int out_size, void* d_ws, size_t ws_size,
                              hipStream_t stream){
  const int*   idx           = (const int*)d_in[0];
  const float* emb           = (const float*)d_in[1];
  const float* pos           = (const float*)d_in[2];
  const float* emb_norm_w    = (const float*)d_in[3];
  const float* token_shift   = (const float*)d_in[4];
  const float* mem_gate_w    = (const float*)d_in[5];
  const float* mem_gate_b    = (const float*)d_in[6];
  const float* memory_p      = (const float*)d_in[7];
  const float* sg_norm       = (const float*)d_in[8];
  const float* sg_down_w     = (const float*)d_in[9];
  const float* sg_down_b     = (const float*)d_in[10];
  const float* sg_up_w       = (const float*)d_in[11];
  const float* sg_up_b       = (const float*)d_in[12];
  const float* final_norm_w  = (const float*)d_in[13];
  struct StackP { const float *nw, *cw, *cb, *w1, *w2, *w3, *kp, *ki, *gn; };
  StackP up { (const float*)d_in[14], (const float*)d_in[15], (const float*)d_in[16],
              (const float*)d_in[17], (const float*)d_in[18], (const float*)d_in[19],
              (const float*)d_in[20], (const float*)d_in[21], (const float*)d_in[23] };
  StackP dn { (const float*)d_in[24], (const float*)d_in[25], (const float*)d_in[26],
              (const float*)d_in[27], (const float*)d_in[28], (const float*)d_in[29],
              (const float*)d_in[30], (const float*)d_in[31], (const float*)d_in[33] };

  char* wp = (char*)d_ws;
  auto alloc = [&](size_t bytes)->void*{
    void* p = (void*)wp; wp += (bytes + 255) & ~(size_t)255; return p;
  };
  float* A0  = (float*)alloc((size_t)NTOK*DIM*4);
  float* A1  = (float*)alloc((size_t)NTOK*DIM*4);
  float* Cb  = (float*)alloc((size_t)NTOK*DIM*4);
  float* Ib  = (float*)alloc((size_t)NTOK*DIM*4);
  float* XIN = (float*)alloc((size_t)NTOK*DIM*4);
  f16*   H1  = (f16*)alloc((size_t)NTOK*DIM*2);
  f16*   HC  = (f16*)alloc((size_t)NTOK*DIM*2);
  f16*   G   = (f16*)alloc((size_t)NTOK*HIDN*2);
  const size_t WSZ = (size_t)NLAYERS*HIDN*DIM;   // per weight family per stack
  f16*   UpW1 = (f16*)alloc(WSZ*2);
  f16*   UpW2 = (f16*)alloc(WSZ*2);
  f16*   UpW3 = (f16*)alloc(WSZ*2);
  f16*   DnW1 = (f16*)alloc(WSZ*2);
  f16*   DnW2 = (f16*)alloc(WSZ*2);
  f16*   DnW3 = (f16*)alloc(WSZ*2);
  f16*   Ef   = (f16*)alloc((size_t)VOCAB*DIM*2);
  float* MEM  = (float*)alloc((size_t)BATCH*DIM*4);

  static const int updil[NLAYERS] = {1,2,4,8,16,32};
  static const int dndil[NLAYERS] = {32,16,8,4,2,1};

  // one-time weight conversions
  {
    long n4 = WSZ/4;
    int g = (int)((n4 + 255)/256);
    k_cvt<<<g,256,0,stream>>>(up.w1, UpW1, n4);
    k_cvt<<<g,256,0,stream>>>(up.w2, UpW2, n4);
    k_cvt<<<g,256,0,stream>>>(up.w3, UpW3, n4);
    k_cvt<<<g,256,0,stream>>>(dn.w1, DnW1, n4);
    k_cvt<<<g,256,0,stream>>>(dn.w2, DnW2, n4);
    k_cvt<<<g,256,0,stream>>>(dn.w3, DnW3, n4);
    long e4 = (long)VOCAB*DIM/4;
    k_cvt<<<(int)((e4+255)/256),256,0,stream>>>(emb, Ef, e4);
  }

  k_embnorm<<<NTOK,64,0,stream>>>(idx, emb, pos, emb_norm_w, Cb);
  k_mem<<<(BATCH*DIM+255)/256,256,0,stream>>>(memory_p, mem_gate_w, mem_gate_b, MEM);
  k_shift<<<NTOK*DIM/256,256,0,stream>>>(Cb, MEM, token_shift, A0);

  auto run_stack = [&](const float* xs, const StackP& S,
                       const f16* W1f, const f16* W2f, const f16* W3f, const int* dil){
    hipMemcpyAsync(Ib, xs, (size_t)NTOK*DIM*4, hipMemcpyDeviceToDevice, stream);
    for (int l=0;l<NLAYERS;l++){
      const float* bin;
      if (l==0){
        bin = xs;
        k_rms<<<NTOK,64,0,stream>>>(xs, S.nw + l*DIM, H1);
      } else {
        k_pid<<<NTOK,64,0,stream>>>(Cb, Ib, 1.f/(float)l,
            S.kp+(l-1)*DIM, S.ki+(l-1)*DIM, S.gn+(l-1)*DIM, S.nw+l*DIM, XIN, H1);
        bin = XIN;
      }
      k_conv<<<NTOK*DIM/256,256,0,stream>>>(H1, S.cw + l*DIM*KSZ, S.cb + l*DIM, HC, dil[l]);
      k_mm<128,64,512,0><<<dim3(NTOK/128, HIDN/64),256,0,stream>>>(
          HC, W1f + (size_t)l*HIDN*DIM, W3f + (size_t)l*HIDN*DIM,
          nullptr, nullptr, nullptr, G);
      k_mm<64,64,1024,1><<<dim3(NTOK/64, DIM/64),256,0,stream>>>(
          G, W2f + (size_t)l*DIM*HIDN, nullptr,
          bin, Cb, Ib, nullptr);
    }
  };

  // stack 1 (up)
  run_stack(A0, up, UpW1, UpW2, UpW3, updil);
  k_mix<<<BATCH*DIM,64,0,stream>>>(Cb);
  k_sgate<<<NTOK,256,0,stream>>>(Cb, A0, sg_norm, sg_down_w, sg_down_b, sg_up_w, sg_up_b, A1);
  // stack 2 (down)
  run_stack(A1, dn, DnW1, DnW2, DnW3, dndil);
  k_mix<<<BATCH*DIM,64,0,stream>>>(Cb);
  k_sgate<<<NTOK,256,0,stream>>>(Cb, A0, sg_norm+DIM, sg_down_w+RANK*DIM, sg_down_b+RANK,
                                 sg_up_w+DIM*RANK, sg_up_b+DIM, A1);
  // stack 3 (up again)
  run_stack(A1, up, UpW1, UpW2, UpW3, updil);
  k_mix<<<BATCH*DIM,64,0,stream>>>(Cb);
  k_sgate<<<NTOK,256,0,stream>>>(Cb, A1, sg_norm+2*DIM, sg_down_w+2*RANK*DIM, sg_down_b+2*RANK,
                                 sg_up_w+2*DIM*RANK, sg_up_b+2*DIM, Cb);
  // final norm + logits (XCD-striped 1-D grid: bid&7 = m-stripe)
  k_rms<<<NTOK,64,0,stream>>>(Cb, final_norm_w, H1);
  k_mm<256,64,512,2><<<8*(VOCAB/64),256,0,stream>>>(
      H1, Ef, nullptr, nullptr, (float*)d_out, nullptr, nullptr);
}

// Round 6
// 2053.851 us; speedup vs baseline: 1.0002x; 1.0002x over previous
//
#include <hip/hip_runtime.h>
#include <math.h>

#define DIM 512
#define NLAYERS 6
#define KSZ 15
#define VOCAB 32000
#define BATCH 2
#define SEQ 1024
#define HIDN 1024
#define RANK 64
#define NTOK (BATCH*SEQ)
#define MIXW 0.1f

typedef unsigned short u16;
typedef _Float16 f16;
typedef _Float16 f16x8 __attribute__((ext_vector_type(8)));
typedef _Float16 f16x4 __attribute__((ext_vector_type(4)));
typedef float  f32x4  __attribute__((ext_vector_type(4)));

__device__ __forceinline__ float sigm(float x){ return 1.f/(1.f+__expf(-x)); }

__device__ __forceinline__ float wred(float v){
  #pragma unroll
  for (int o=32;o>0;o>>=1) v += __shfl_xor(v, o, 64);
  return v;
}

#define MFMA16(a,b,c) __builtin_amdgcn_mfma_f32_16x16x32_f16(a,b,c,0,0,0)

// ---------------- f32 -> f16 weight conversion ----------------
__global__ __launch_bounds__(256) void k_cvt(const float* __restrict__ s,
    f16* __restrict__ d, long n4){
  long i = (long)blockIdx.x*256 + threadIdx.x;
  if (i >= n4) return;
  float4 v = reinterpret_cast<const float4*>(s)[i];
  f16x4 o; o.x=(f16)v.x; o.y=(f16)v.y; o.z=(f16)v.z; o.w=(f16)v.w;
  reinterpret_cast<f16x4*>(d)[i] = o;
}

// ---------------- front-end ----------------
__global__ __launch_bounds__(64) void k_embnorm(const int* __restrict__ idx,
    const float* __restrict__ emb, const float* __restrict__ pos,
    const float* __restrict__ w, float* __restrict__ out){
  int row = blockIdx.x;                 // b*SEQ + t
  int t = row & (SEQ-1);
  int lane = threadIdx.x;
  long ebase = (long)idx[row]*DIM;
  long pbase = (long)t*DIM;
  float v[8]; float ss = 0.f;
  #pragma unroll
  for (int c=0;c<2;c++){
    int d = c*256 + lane*4;
    float4 e = *reinterpret_cast<const float4*>(emb + ebase + d);
    float4 p = *reinterpret_cast<const float4*>(pos + pbase + d);
    float x0 = e.x+p.x, x1 = e.y+p.y, x2 = e.z+p.z, x3 = e.w+p.w;
    v[c*4+0]=x0; v[c*4+1]=x1; v[c*4+2]=x2; v[c*4+3]=x3;
    ss += x0*x0 + x1*x1 + x2*x2 + x3*x3;
  }
  ss = wred(ss);
  float rs = rsqrtf(ss*(1.f/DIM) + 1e-6f);
  long ob = (long)row*DIM;
  #pragma unroll
  for (int c=0;c<2;c++){
    int d = c*256 + lane*4;
    float4 wv = *reinterpret_cast<const float4*>(w + d);
    float4 o;
    o.x = v[c*4+0]*rs*wv.x; o.y = v[c*4+1]*rs*wv.y;
    o.z = v[c*4+2]*rs*wv.z; o.w = v[c*4+3]*rs*wv.w;
    *reinterpret_cast<float4*>(out + ob + d) = o;
  }
}

__global__ void k_mem(const float* __restrict__ p, const float* __restrict__ gw,
                      const float* __restrict__ gb, float* __restrict__ mem){
  int i = blockIdx.x*blockDim.x + threadIdx.x;
  if (i >= BATCH*DIM) return;
  int b = i >> 9, d = i & (DIM-1);
  float acc = gb[d];
  const float* wr = gw + (long)d*DIM;
  const float* pr = p + b*DIM;
  for (int k=0;k<DIM;k+=4){
    float4 wv = *reinterpret_cast<const float4*>(wr+k);
    float4 pv = *reinterpret_cast<const float4*>(pr+k);
    acc += wv.x*pv.x + wv.y*pv.y + wv.z*pv.z + wv.w*pv.w;
  }
  mem[i] = sigm(acc);
}

__global__ void k_shift(const float* __restrict__ xn, const float* __restrict__ mem,
    const float* __restrict__ ts, float* __restrict__ out){
  int i = blockIdx.x*256 + threadIdx.x;   // over NTOK*DIM
  int d = i & (DIM-1); int row = i >> 9; int t = row & (SEQ-1); int b = row >> 10;
  float cur = xn[i];
  float v;
  if (t == 0) v = cur;
  else { float f = ts[d]; v = f*xn[i-DIM] + (1.f-f)*cur; }
  out[i] = v + mem[b*DIM + d];
}

// ---------------- norms / pid (f32 in, f16 out) ----------------
__global__ __launch_bounds__(64) void k_rms(const float* __restrict__ x,
    const float* __restrict__ w, f16* __restrict__ oh){
  int row = blockIdx.x; int lane = threadIdx.x;
  const float* xr = x + (long)row*DIM;
  float v[8]; float ss = 0.f;
  #pragma unroll
  for (int c=0;c<2;c++){
    int d = c*256 + lane*4;
    float4 f = *reinterpret_cast<const float4*>(xr + d);
    v[c*4+0]=f.x; v[c*4+1]=f.y; v[c*4+2]=f.z; v[c*4+3]=f.w;
    ss += f.x*f.x + f.y*f.y + f.z*f.z + f.w*f.w;
  }
  ss = wred(ss);
  float rs = rsqrtf(ss*(1.f/DIM) + 1e-6f);
  long ob = (long)row*DIM;
  #pragma unroll
  for (int c=0;c<2;c++){
    int d = c*256 + lane*4;
    float4 wv = *reinterpret_cast<const float4*>(w + d);
    f16x4 o;
    o.x = (f16)(v[c*4+0]*rs*wv.x); o.y = (f16)(v[c*4+1]*rs*wv.y);
    o.z = (f16)(v[c*4+2]*rs*wv.z); o.w = (f16)(v[c*4+3]*rs*wv.w);
    *reinterpret_cast<f16x4*>(oh + ob + d) = o;
  }
}

// cur_in = rmsnorm(silu(kp*C + ki*(I/i)), gn);  h1 = f16(rmsnorm(cur_in, nw))
__global__ __launch_bounds__(64) void k_pid(const float* __restrict__ C,
    const float* __restrict__ I, float inv_i,
    const float* __restrict__ kp, const float* __restrict__ ki,
    const float* __restrict__ gn, const float* __restrict__ nw,
    float* __restrict__ xin, f16* __restrict__ oh){
  int row = blockIdx.x; int lane = threadIdx.x;
  long base = (long)row*DIM;
  float u[8]; float ss = 0.f;
  #pragma unroll
  for (int c=0;c<2;c++){
    int d = c*256 + lane*4;
    float4 cv = *reinterpret_cast<const float4*>(C + base + d);
    float4 iv = *reinterpret_cast<const float4*>(I + base + d);
    float4 kpv = *reinterpret_cast<const float4*>(kp + d);
    float4 kiv = *reinterpret_cast<const float4*>(ki + d);
    float p0 = kpv.x*cv.x + kiv.x*(iv.x*inv_i);
    float p1 = kpv.y*cv.y + kiv.y*(iv.y*inv_i);
    float p2 = kpv.z*cv.z + kiv.z*(iv.z*inv_i);
    float p3 = kpv.w*cv.w + kiv.w*(iv.w*inv_i);
    float s0 = p0*sigm(p0), s1 = p1*sigm(p1), s2 = p2*sigm(p2), s3 = p3*sigm(p3);
    u[c*4+0]=s0; u[c*4+1]=s1; u[c*4+2]=s2; u[c*4+3]=s3;
    ss += s0*s0 + s1*s1 + s2*s2 + s3*s3;
  }
  ss = wred(ss);
  float rs1 = rsqrtf(ss*(1.f/DIM) + 1e-6f);
  float x2[8]; float ss2 = 0.f;
  #pragma unroll
  for (int c=0;c<2;c++){
    int d = c*256 + lane*4;
    float4 gv = *reinterpret_cast<const float4*>(gn + d);
    float y0 = u[c*4+0]*rs1*gv.x, y1 = u[c*4+1]*rs1*gv.y;
    float y2 = u[c*4+2]*rs1*gv.z, y3 = u[c*4+3]*rs1*gv.w;
    x2[c*4+0]=y0; x2[c*4+1]=y1; x2[c*4+2]=y2; x2[c*4+3]=y3;
    ss2 += y0*y0 + y1*y1 + y2*y2 + y3*y3;
    float4 o; o.x=y0; o.y=y1; o.z=y2; o.w=y3;
    *reinterpret_cast<float4*>(xin + base + d) = o;
  }
  ss2 = wred(ss2);
  float rs2 = rsqrtf(ss2*(1.f/DIM) + 1e-6f);
  #pragma unroll
  for (int c=0;c<2;c++){
    int d = c*256 + lane*4;
    float4 nv = *reinterpret_cast<const float4*>(nw + d);
    f16x4 o;
    o.x = (f16)(x2[c*4+0]*rs2*nv.x); o.y = (f16)(x2[c*4+1]*rs2*nv.y);
    o.z = (f16)(x2[c*4+2]*rs2*nv.z); o.w = (f16)(x2[c*4+3]*rs2*nv.w);
    *reinterpret_cast<f16x4*>(oh + base + d) = o;
  }
}

// ---------------- depthwise causal conv + silu ----------------
__global__ void k_conv(const f16* __restrict__ h1,
    const float* __restrict__ cw, const float* __restrict__ cb,
    f16* __restrict__ hc, int dil){
  int i = blockIdx.x*256 + threadIdx.x;   // over NTOK*DIM
  int d = i & (DIM-1); int row = i >> 9; int t = row & (SEQ-1);
  float acc = cb[d];
  const float* wr = cw + d*KSZ;
  #pragma unroll
  for (int m=0;m<KSZ;m++){
    if (t - m*dil >= 0) acc += wr[KSZ-1-m] * (float)h1[i - m*dil*DIM];
  }
  float s = acc * sigm(acc);
  hc[i] = (f16)s;
}

// ---------------- unified tiled MFMA GEMM ----------------
// C[M,N] = A[M,K] . B[N,K]^T, f16 operands, f32 accumulate. 4 waves split M.
// EPI 0: dual (B0=W1,B1=W3): OH = f16(silu(c0)*c1), ld HIDN
// EPI 1: w2: val = c0 + XIN; OF = val; I += val (ld DIM)
// EPI 2: logits: OF = c0 (ld VOCAB); 1-D grid, XCD-striped (mt = bid&7)
template<int BM,int BN,int KD,int EPI>
__global__ __launch_bounds__(256) void k_mm(
    const f16* __restrict__ A, const f16* __restrict__ B0, const f16* __restrict__ B1,
    const float* __restrict__ XIN, float* __restrict__ OF, float* __restrict__ I,
    f16* __restrict__ OH){
  constexpr int WM = BM/4, MF = WM/16, NF = BN/16;   // per-wave: WM x BN
  constexpr int ACH = BM*64/2048;       // 16B chunks per thread for A tile (BM x 64)
  constexpr int BCH = BN*64/2048;       // per B matrix
  constexpr int NMAT = (EPI==0) ? 2 : 1;
  constexpr int SAB = (BM*64 + NMAT*BN*64)*2;
  constexpr int STGB = 4*16*68*4;
  constexpr int SMEMB = SAB > STGB ? SAB : STGB;
  __shared__ char smem[SMEMB];
  f16* sA = (f16*)smem;
  f16* sB = (f16*)(smem + (size_t)BM*64*2);
  int tid = threadIdx.x;
  int lane = tid & 63, wid = tid >> 6;
  int m0, n0;
  if constexpr (EPI==2){ int bid = blockIdx.x; m0 = (bid&7)*BM; n0 = (bid>>3)*BN; }
  else { m0 = blockIdx.x*BM; n0 = blockIdx.y*BN; }

  float4 ra[ACH], rb0[BCH], rb1[(EPI==0)?BCH:1];

  auto loadT = [&](int k0){
    #pragma unroll
    for (int c=0;c<ACH;c++){
      int cc = c*256 + tid; int row = cc>>3, kp = cc&7;
      ra[c] = *reinterpret_cast<const float4*>(A + (size_t)(m0+row)*KD + k0 + kp*8);
    }
    #pragma unroll
    for (int c=0;c<BCH;c++){
      int cc = c*256 + tid; int row = cc>>3, kp = cc&7;
      rb0[c] = *reinterpret_cast<const float4*>(B0 + (size_t)(n0+row)*KD + k0 + kp*8);
      if constexpr (EPI==0)
        rb1[c] = *reinterpret_cast<const float4*>(B1 + (size_t)(n0+row)*KD + k0 + kp*8);
    }
  };

  f32x4 acc0[MF][NF] = {};
  f32x4 acc1[MF][NF] = {};

  loadT(0);
  int k0 = 0;
  while (true){
    __syncthreads();
    // swizzled LDS write: 16B slot index kp -> kp ^ (row&7)  (BK=64 f16 = 128B rows)
    #pragma unroll
    for (int c=0;c<ACH;c++){
      int cc = c*256 + tid; int row = cc>>3, kp = cc&7;
      *reinterpret_cast<float4*>(&sA[row*64 + (kp^(row&7))*8]) = ra[c];
    }
    #pragma unroll
    for (int c=0;c<BCH;c++){
      int cc = c*256 + tid; int row = cc>>3, kp = cc&7;
      *reinterpret_cast<float4*>(&sB[row*64 + (kp^(row&7))*8]) = rb0[c];
      if constexpr (EPI==0)
        *reinterpret_cast<float4*>(&sB[BN*64 + row*64 + (kp^(row&7))*8]) = rb1[c];
    }
    __syncthreads();
    int knext = k0 + 64;
    if (knext < KD) loadT(knext);   // prefetch overlaps MFMA below
    #pragma unroll
    for (int kk=0;kk<2;kk++){
      int kp0 = kk*4 + (lane>>4);   // 16B chunk 0..7 within row
      f16x8 af[MF], bf[NF], bg[(EPI==0)?NF:1];
      #pragma unroll
      for (int mf=0;mf<MF;mf++){
        int row = wid*WM + mf*16 + (lane&15);
        af[mf] = *reinterpret_cast<const f16x8*>(&sA[row*64 + (kp0^(row&7))*8]);
      }
      #pragma unroll
      for (int nf=0;nf<NF;nf++){
        int row = nf*16 + (lane&15);
        bf[nf] = *reinterpret_cast<const f16x8*>(&sB[row*64 + (kp0^(row&7))*8]);
        if constexpr (EPI==0)
          bg[nf] = *reinterpret_cast<const f16x8*>(&sB[BN*64 + row*64 + (kp0^(row&7))*8]);
      }
      #pragma unroll
      for (int mf=0;mf<MF;mf++){
        #pragma unroll
        for (int nf=0;nf<NF;nf++){
          acc0[mf][nf] = MFMA16(af[mf], bf[nf], acc0[mf][nf]);
          if constexpr (EPI==0)
            acc1[mf][nf] = MFMA16(af[mf], bg[nf], acc1[mf][nf]);
        }
      }
    }
    k0 = knext;
    if (k0 >= KD) break;
  }

  // ---- LDS-staged coalesced epilogue (wave-private staging, stride 68) ----
  __syncthreads();                       // done with sA/sB; reuse as staging
  float* stg = (float*)smem + wid*(16*68);
  int dr = (lane>>4)*4, dc = lane&15;
  #pragma unroll
  for (int mf=0;mf<MF;mf++){
    #pragma unroll
    for (int nf=0;nf<NF;nf++){
      #pragma unroll
      for (int q=0;q<4;q++){
        float v;
        if constexpr (EPI==0){
          float x1 = acc0[mf][nf][q];
          v = x1*sigm(x1)*acc1[mf][nf][q];
        } else v = acc0[mf][nf][q];
        stg[(dr+q)*68 + nf*16 + dc] = v;
      }
    }
    int gmb = m0 + wid*WM + mf*16;
    if constexpr (EPI==0){
      #pragma unroll
      for (int pass=0;pass<2;pass++){
        int r = pass*8 + (lane>>3);
        int c = 8*(lane&7);
        float4 lo = *reinterpret_cast<float4*>(&stg[r*68 + c]);
        float4 hi = *reinterpret_cast<float4*>(&stg[r*68 + c + 4]);
        f16x8 o;
        o[0]=(f16)lo.x; o[1]=(f16)lo.y; o[2]=(f16)lo.z; o[3]=(f16)lo.w;
        o[4]=(f16)hi.x; o[5]=(f16)hi.y; o[6]=(f16)hi.z; o[7]=(f16)hi.w;
        *reinterpret_cast<f16x8*>(&OH[(size_t)(gmb+r)*HIDN + n0 + c]) = o;
      }
    } else if constexpr (EPI==1){
      #pragma unroll
      for (int pass=0;pass<4;pass++){
        int r = pass*4 + (lane>>4);
        int c = 4*(lane&15);
        float4 v = *reinterpret_cast<float4*>(&stg[r*68 + c]);
        size_t o = (size_t)(gmb+r)*DIM + n0 + c;
        float4 x = *reinterpret_cast<const float4*>(&XIN[o]);
        v.x += x.x; v.y += x.y; v.z += x.z; v.w += x.w;
        *reinterpret_cast<float4*>(&OF[o]) = v;
        float4 iv = *reinterpret_cast<const float4*>(&I[o]);
        iv.x += v.x; iv.y += v.y; iv.z += v.z; iv.w += v.w;
        *reinterpret_cast<float4*>(&I[o]) = iv;
      }
    } else {
      #pragma unroll
      for (int pass=0;pass<4;pass++){
        int r = pass*4 + (lane>>4);
        int c = 4*(lane&15);
        float4 v = *reinterpret_cast<float4*>(&stg[r*68 + c]);
        *reinterpret_cast<float4*>(&OF[(size_t)(gmb+r)*VOCAB + n0 + c]) = v;
      }
    }
  }
}

// ---------------- mix: parallel scan, one wave per (b,d) column ----------------
__global__ __launch_bounds__(64) void k_mix(float* __restrict__ x){
  int col = blockIdx.x;                 // 0..BATCH*DIM-1
  int b = col >> 9, d = col & (DIM-1);
  int lane = threadIdx.x;
  long o = (long)b*SEQ*DIM + d + (long)lane*16*DIM;
  float v[16]; float s = 0.f;
  #pragma unroll
  for (int j=0;j<16;j++){ v[j] = x[o + (long)j*DIM]; s += v[j]; }
  float t = s;
  #pragma unroll
  for (int off=1; off<64; off<<=1){
    float u = __shfl_up(t, off, 64);
    if (lane >= off) t += u;
  }
  float run = t - s;   // exclusive prefix
  #pragma unroll
  for (int j=0;j<16;j++){
    run += v[j];
    int tt = lane*16 + j;
    x[o + (long)j*DIM] = v[j] + MIXW*run/(float)(tt+1);
  }
}

// ---------------- sgate (low-rank gate) ----------------
__global__ __launch_bounds__(256) void k_sgate(const float* __restrict__ xnew,
    const float* __restrict__ xold, const float* __restrict__ nw,
    const float* __restrict__ dw, const float* __restrict__ db,
    const float* __restrict__ uw, const float* __restrict__ ub,
    float* __restrict__ out){
  __shared__ float raw[DIM];
  __shared__ float xn[DIM];
  __shared__ float part[256];
  __shared__ float hb[RANK];
  int row = blockIdx.x, tid = threadIdx.x;
  long base = (long)row*DIM;
  float ss = 0.f;
  for (int d=tid; d<DIM; d+=256){ float v = xnew[base+d]; raw[d]=v; ss += v*v; }
  ss = wred(ss);
  if ((tid&63)==0) part[tid>>6] = ss;
  __syncthreads();
  float tot = part[0]+part[1]+part[2]+part[3];
  float rs = rsqrtf(tot*(1.f/DIM)+1e-6f);
  for (int d=tid; d<DIM; d+=256) xn[d] = raw[d]*rs*nw[d];
  __syncthreads();
  int rr = tid & 63, q = tid >> 6;
  float p = 0.f;
  const float* dwr = dw + (long)rr*DIM + q*128;
  const float* xq = xn + q*128;
  #pragma unroll 8
  for (int d=0; d<128; d+=4){
    float4 wv = *reinterpret_cast<const float4*>(dwr+d);
    p += xq[d]*wv.x + xq[d+1]*wv.y + xq[d+2]*wv.z + xq[d+3]*wv.w;
  }
  part[tid] = p;
  __syncthreads();
  if (tid < RANK){
    float h = part[tid] + part[64+tid] + part[128+tid] + part[192+tid] + db[tid];
    hb[tid] = h * sigm(h);
  }
  __syncthreads();
  for (int d=tid; d<DIM; d+=256){
    float a = ub[d];
    const float* ur = uw + (long)d*RANK;
    #pragma unroll
    for (int rj=0;rj<RANK;rj+=4){
      float4 uv = *reinterpret_cast<const float4*>(ur+rj);
      a += hb[rj]*uv.x + hb[rj+1]*uv.y + hb[rj+2]*uv.z + hb[rj+3]*uv.w;
    }
    float g = sigm(a);
    out[base+d] = g*raw[d] + (1.f-g)*xold[base+d];
  }
}

// ---------------- host orchestration ----------------
extern "C" void kernel_launch(void* const* d_in, const int* in_sizes, int n_in,
                              void* d_out, int out_size, void* d_ws, size_t ws_size,
                              hipStream_t stream){
  const int*   idx           = (const int*)d_in[0];
  const float* emb           = (const float*)d_in[1];
  const float* pos           = (const float*)d_in[2];
  const float* emb_norm_w    = (const float*)d_in[3];
  const float* token_shift   = (const float*)d_in[4];
  const float* mem_gate_w    = (const float*)d_in[5];
  const float* mem_gate_b    = (const float*)d_in[6];
  const float* memory_p      = (const float*)d_in[7];
  const float* sg_norm       = (const float*)d_in[8];
  const float* sg_down_w     = (const float*)d_in[9];
  const float* sg_down_b     = (const float*)d_in[10];
  const float* sg_up_w       = (const float*)d_in[11];
  const float* sg_up_b       = (const float*)d_in[12];
  const float* final_norm_w  = (const float*)d_in[13];
  struct StackP { const float *nw, *cw, *cb, *w1, *w2, *w3, *kp, *ki, *gn; };
  StackP up { (const float*)d_in[14], (const float*)d_in[15], (const float*)d_in[16],
              (const float*)d_in[17], (const float*)d_in[18], (const float*)d_in[19],
              (const float*)d_in[20], (const float*)d_in[21], (const float*)d_in[23] };
  StackP dn { (const float*)d_in[24], (const float*)d_in[25], (const float*)d_in[26],
              (const float*)d_in[27], (const float*)d_in[28], (const float*)d_in[29],
              (const float*)d_in[30], (const float*)d_in[31], (const float*)d_in[33] };

  char* wp = (char*)d_ws;
  auto alloc = [&](size_t bytes)->void*{
    void* p = (void*)wp; wp += (bytes + 255) & ~(size_t)255; return p;
  };
  float* A0  = (float*)alloc((size_t)NTOK*DIM*4);
  float* A1  = (float*)alloc((size_t)NTOK*DIM*4);
  float* Cb  = (float*)alloc((size_t)NTOK*DIM*4);
  float* Ib  = (float*)alloc((size_t)NTOK*DIM*4);
  float* XIN = (float*)alloc((size_t)NTOK*DIM*4);
  f16*   H1  = (f16*)alloc((size_t)NTOK*DIM*2);
  f16*   HC  = (f16*)alloc((size_t)NTOK*DIM*2);
  f16*   G   = (f16*)alloc((size_t)NTOK*HIDN*2);
  const size_t WSZ = (size_t)NLAYERS*HIDN*DIM;   // per weight family per stack
  f16*   UpW1 = (f16*)alloc(WSZ*2);
  f16*   UpW2 = (f16*)alloc(WSZ*2);
  f16*   UpW3 = (f16*)alloc(WSZ*2);
  f16*   DnW1 = (f16*)alloc(WSZ*2);
  f16*   DnW2 = (f16*)alloc(WSZ*2);
  f16*   DnW3 = (f16*)alloc(WSZ*2);
  f16*   Ef   = (f16*)alloc((size_t)VOCAB*DIM*2);
  float* MEM  = (float*)alloc((size_t)BATCH*DIM*4);

  static const int updil[NLAYERS] = {1,2,4,8,16,32};
  static const int dndil[NLAYERS] = {32,16,8,4,2,1};

  // one-time weight conversions
  {
    long n4 = WSZ/4;
    int g = (int)((n4 + 255)/256);
    k_cvt<<<g,256,0,stream>>>(up.w1, UpW1, n4);
    k_cvt<<<g,256,0,stream>>>(up.w2, UpW2, n4);
    k_cvt<<<g,256,0,stream>>>(up.w3, UpW3, n4);
    k_cvt<<<g,256,0,stream>>>(dn.w1, DnW1, n4);
    k_cvt<<<g,256,0,stream>>>(dn.w2, DnW2, n4);
    k_cvt<<<g,256,0,stream>>>(dn.w3, DnW3, n4);
    long e4 = (long)VOCAB*DIM/4;
    k_cvt<<<(int)((e4+255)/256),256,0,stream>>>(emb, Ef, e4);
  }

  k_embnorm<<<NTOK,64,0,stream>>>(idx, emb, pos, emb_norm_w, Cb);
  k_mem<<<(BATCH*DIM+255)/256,256,0,stream>>>(memory_p, mem_gate_w, mem_gate_b, MEM);
  k_shift<<<NTOK*DIM/256,256,0,stream>>>(Cb, MEM, token_shift, A0);

  auto run_stack = [&](const float* xs, const StackP& S,
                       const f16* W1f, const f16* W2f, const f16* W3f, const int* dil){
    hipMemcpyAsync(Ib, xs, (size_t)NTOK*DIM*4, hipMemcpyDeviceToDevice, stream);
    for (int l=0;l<NLAYERS;l++){
      const float* bin;
      if (l==0){
        bin = xs;
        k_rms<<<NTOK,64,0,stream>>>(xs, S.nw + l*DIM, H1);
      } else {
        k_pid<<<NTOK,64,0,stream>>>(Cb, Ib, 1.f/(float)l,
            S.kp+(l-1)*DIM, S.ki+(l-1)*DIM, S.gn+(l-1)*DIM, S.nw+l*DIM, XIN, H1);
        bin = XIN;
      }
      k_conv<<<NTOK*DIM/256,256,0,stream>>>(H1, S.cw + l*DIM*KSZ, S.cb + l*DIM, HC, dil[l]);
      k_mm<128,64,512,0><<<dim3(NTOK/128, HIDN/64),256,0,stream>>>(
          HC, W1f + (size_t)l*HIDN*DIM, W3f + (size_t)l*HIDN*DIM,
          nullptr, nullptr, nullptr, G);
      k_mm<64,64,1024,1><<<dim3(NTOK/64, DIM/64),256,0,stream>>>(
          G, W2f + (size_t)l*DIM*HIDN, nullptr,
          bin, Cb, Ib, nullptr);
    }
  };

  // stack 1 (up)
  run_stack(A0, up, UpW1, UpW2, UpW3, updil);
  k_mix<<<BATCH*DIM,64,0,stream>>>(Cb);
  k_sgate<<<NTOK,256,0,stream>>>(Cb, A0, sg_norm, sg_down_w, sg_down_b, sg_up_w, sg_up_b, A1);
  // stack 2 (down)
  run_stack(A1, dn, DnW1, DnW2, DnW3, dndil);
  k_mix<<<BATCH*DIM,64,0,stream>>>(Cb);
  k_sgate<<<NTOK,256,0,stream>>>(Cb, A0, sg_norm+DIM, sg_down_w+RANK*DIM, sg_down_b+RANK,
                                 sg_up_w+DIM*RANK, sg_up_b+DIM, A1);
  // stack 3 (up again)
  run_stack(A1, up, UpW1, UpW2, UpW3, updil);
  k_mix<<<BATCH*DIM,64,0,stream>>>(Cb);
  k_sgate<<<NTOK,256,0,stream>>>(Cb, A1, sg_norm+2*DIM, sg_down_w+2*RANK*DIM, sg_down_b+2*RANK,
                                 sg_up_w+2*DIM*RANK, sg_up_b+2*DIM, Cb);
  // final norm + logits (XCD-striped 1-D grid: bid&7 = m-stripe)
  k_rms<<<NTOK,64,0,stream>>>(Cb, final_norm_w, H1);
  k_mm<256,64,512,2><<<8*(VOCAB/64),256,0,stream>>>(
      H1, Ef, nullptr, nullptr, (float*)d_out, nullptr, nullptr);
}

// Round 7
// 1092.530 us; speedup vs baseline: 1.8803x; 1.8799x over previous
//
#include <hip/hip_runtime.h>
#include <math.h>

#define DIM 512
#define NLAYERS 6
#define KSZ 15
#define VOCAB 32000
#define BATCH 2
#define SEQ 1024
#define HIDN 1024
#define RANK 64
#define NTOK (BATCH*SEQ)
#define MIXW 0.1f

typedef unsigned short u16;
typedef _Float16 f16;
typedef _Float16 f16x8 __attribute__((ext_vector_type(8)));
typedef _Float16 f16x4 __attribute__((ext_vector_type(4)));
typedef float  f32x4  __attribute__((ext_vector_type(4)));

__device__ __forceinline__ float sigm(float x){ return 1.f/(1.f+__expf(-x)); }

__device__ __forceinline__ float wred(float v){
  #pragma unroll
  for (int o=32;o>0;o>>=1) v += __shfl_xor(v, o, 64);
  return v;
}

#define MFMA16(a,b,c) __builtin_amdgcn_mfma_f32_16x16x32_f16(a,b,c,0,0,0)

// async global->LDS, 16B per lane, dest = uniform base + lane*16
__device__ __forceinline__ void gld16(const f16* g, f16* l){
  __builtin_amdgcn_global_load_lds(
      (const __attribute__((address_space(1))) void*)g,
      (__attribute__((address_space(3))) void*)l, 16, 0, 0);
}

// ---------------- f32 -> f16 weight conversion ----------------
__global__ __launch_bounds__(256) void k_cvt(const float* __restrict__ s,
    f16* __restrict__ d, long n4){
  long i = (long)blockIdx.x*256 + threadIdx.x;
  if (i >= n4) return;
  float4 v = reinterpret_cast<const float4*>(s)[i];
  f16x4 o; o.x=(f16)v.x; o.y=(f16)v.y; o.z=(f16)v.z; o.w=(f16)v.w;
  reinterpret_cast<f16x4*>(d)[i] = o;
}

// conv weight transpose: cwT[l][m][d] = cw[l][d][KSZ-1-m]
__global__ __launch_bounds__(256) void k_cvtconv(const float* __restrict__ cw,
    float* __restrict__ cwT, int n){
  int i = blockIdx.x*256 + threadIdx.x;
  if (i >= n) return;
  int d = i & (DIM-1); int m = (i >> 9) % KSZ; int l = i / (KSZ*DIM);
  cwT[i] = cw[((size_t)l*DIM + d)*KSZ + (KSZ-1-m)];
}

// ---------------- front-end ----------------
__global__ __launch_bounds__(64) void k_embnorm(const int* __restrict__ idx,
    const float* __restrict__ emb, const float* __restrict__ pos,
    const float* __restrict__ w, float* __restrict__ out){
  int row = blockIdx.x;                 // b*SEQ + t
  int t = row & (SEQ-1);
  int lane = threadIdx.x;
  long ebase = (long)idx[row]*DIM;
  long pbase = (long)t*DIM;
  float v[8]; float ss = 0.f;
  #pragma unroll
  for (int c=0;c<2;c++){
    int d = c*256 + lane*4;
    float4 e = *reinterpret_cast<const float4*>(emb + ebase + d);
    float4 p = *reinterpret_cast<const float4*>(pos + pbase + d);
    float x0 = e.x+p.x, x1 = e.y+p.y, x2 = e.z+p.z, x3 = e.w+p.w;
    v[c*4+0]=x0; v[c*4+1]=x1; v[c*4+2]=x2; v[c*4+3]=x3;
    ss += x0*x0 + x1*x1 + x2*x2 + x3*x3;
  }
  ss = wred(ss);
  float rs = rsqrtf(ss*(1.f/DIM) + 1e-6f);
  long ob = (long)row*DIM;
  #pragma unroll
  for (int c=0;c<2;c++){
    int d = c*256 + lane*4;
    float4 wv = *reinterpret_cast<const float4*>(w + d);
    float4 o;
    o.x = v[c*4+0]*rs*wv.x; o.y = v[c*4+1]*rs*wv.y;
    o.z = v[c*4+2]*rs*wv.z; o.w = v[c*4+3]*rs*wv.w;
    *reinterpret_cast<float4*>(out + ob + d) = o;
  }
}

__global__ void k_mem(const float* __restrict__ p, const float* __restrict__ gw,
                      const float* __restrict__ gb, float* __restrict__ mem){
  int i = blockIdx.x*blockDim.x + threadIdx.x;
  if (i >= BATCH*DIM) return;
  int b = i >> 9, d = i & (DIM-1);
  float acc = gb[d];
  const float* wr = gw + (long)d*DIM;
  const float* pr = p + b*DIM;
  for (int k=0;k<DIM;k+=4){
    float4 wv = *reinterpret_cast<const float4*>(wr+k);
    float4 pv = *reinterpret_cast<const float4*>(pr+k);
    acc += wv.x*pv.x + wv.y*pv.y + wv.z*pv.z + wv.w*pv.w;
  }
  mem[i] = sigm(acc);
}

__global__ void k_shift(const float* __restrict__ xn, const float* __restrict__ mem,
    const float* __restrict__ ts, float* __restrict__ out){
  int i = blockIdx.x*256 + threadIdx.x;   // over NTOK*DIM
  int d = i & (DIM-1); int row = i >> 9; int t = row & (SEQ-1); int b = row >> 10;
  float cur = xn[i];
  float v;
  if (t == 0) v = cur;
  else { float f = ts[d]; v = f*xn[i-DIM] + (1.f-f)*cur; }
  out[i] = v + mem[b*DIM + d];
}

// ---------------- norms / pid (f32 in, f16 out) ----------------
__global__ __launch_bounds__(64) void k_rms(const float* __restrict__ x,
    const float* __restrict__ w, f16* __restrict__ oh){
  int row = blockIdx.x; int lane = threadIdx.x;
  const float* xr = x + (long)row*DIM;
  float v[8]; float ss = 0.f;
  #pragma unroll
  for (int c=0;c<2;c++){
    int d = c*256 + lane*4;
    float4 f = *reinterpret_cast<const float4*>(xr + d);
    v[c*4+0]=f.x; v[c*4+1]=f.y; v[c*4+2]=f.z; v[c*4+3]=f.w;
    ss += f.x*f.x + f.y*f.y + f.z*f.z + f.w*f.w;
  }
  ss = wred(ss);
  float rs = rsqrtf(ss*(1.f/DIM) + 1e-6f);
  long ob = (long)row*DIM;
  #pragma unroll
  for (int c=0;c<2;c++){
    int d = c*256 + lane*4;
    float4 wv = *reinterpret_cast<const float4*>(w + d);
    f16x4 o;
    o.x = (f16)(v[c*4+0]*rs*wv.x); o.y = (f16)(v[c*4+1]*rs*wv.y);
    o.z = (f16)(v[c*4+2]*rs*wv.z); o.w = (f16)(v[c*4+3]*rs*wv.w);
    *reinterpret_cast<f16x4*>(oh + ob + d) = o;
  }
}

// cur_in = rmsnorm(silu(kp*C + ki*(I/i)), gn);  h1 = f16(rmsnorm(cur_in, nw))
__global__ __launch_bounds__(64) void k_pid(const float* __restrict__ C,
    const float* __restrict__ I, float inv_i,
    const float* __restrict__ kp, const float* __restrict__ ki,
    const float* __restrict__ gn, const float* __restrict__ nw,
    float* __restrict__ xin, f16* __restrict__ oh){
  int row = blockIdx.x; int lane = threadIdx.x;
  long base = (long)row*DIM;
  float u[8]; float ss = 0.f;
  #pragma unroll
  for (int c=0;c<2;c++){
    int d = c*256 + lane*4;
    float4 cv = *reinterpret_cast<const float4*>(C + base + d);
    float4 iv = *reinterpret_cast<const float4*>(I + base + d);
    float4 kpv = *reinterpret_cast<const float4*>(kp + d);
    float4 kiv = *reinterpret_cast<const float4*>(ki + d);
    float p0 = kpv.x*cv.x + kiv.x*(iv.x*inv_i);
    float p1 = kpv.y*cv.y + kiv.y*(iv.y*inv_i);
    float p2 = kpv.z*cv.z + kiv.z*(iv.z*inv_i);
    float p3 = kpv.w*cv.w + kiv.w*(iv.w*inv_i);
    float s0 = p0*sigm(p0), s1 = p1*sigm(p1), s2 = p2*sigm(p2), s3 = p3*sigm(p3);
    u[c*4+0]=s0; u[c*4+1]=s1; u[c*4+2]=s2; u[c*4+3]=s3;
    ss += s0*s0 + s1*s1 + s2*s2 + s3*s3;
  }
  ss = wred(ss);
  float rs1 = rsqrtf(ss*(1.f/DIM) + 1e-6f);
  float x2[8]; float ss2 = 0.f;
  #pragma unroll
  for (int c=0;c<2;c++){
    int d = c*256 + lane*4;
    float4 gv = *reinterpret_cast<const float4*>(gn + d);
    float y0 = u[c*4+0]*rs1*gv.x, y1 = u[c*4+1]*rs1*gv.y;
    float y2 = u[c*4+2]*rs1*gv.z, y3 = u[c*4+3]*rs1*gv.w;
    x2[c*4+0]=y0; x2[c*4+1]=y1; x2[c*4+2]=y2; x2[c*4+3]=y3;
    ss2 += y0*y0 + y1*y1 + y2*y2 + y3*y3;
    float4 o; o.x=y0; o.y=y1; o.z=y2; o.w=y3;
    *reinterpret_cast<float4*>(xin + base + d) = o;
  }
  ss2 = wred(ss2);
  float rs2 = rsqrtf(ss2*(1.f/DIM) + 1e-6f);
  #pragma unroll
  for (int c=0;c<2;c++){
    int d = c*256 + lane*4;
    float4 nv = *reinterpret_cast<const float4*>(nw + d);
    f16x4 o;
    o.x = (f16)(x2[c*4+0]*rs2*nv.x); o.y = (f16)(x2[c*4+1]*rs2*nv.y);
    o.z = (f16)(x2[c*4+2]*rs2*nv.z); o.w = (f16)(x2[c*4+3]*rs2*nv.w);
    *reinterpret_cast<f16x4*>(oh + base + d) = o;
  }
}

// ---------------- depthwise causal conv + silu (cwT: [m][d] transposed) ----------------
__global__ void k_conv(const f16* __restrict__ h1,
    const float* __restrict__ cwT, const float* __restrict__ cb,
    f16* __restrict__ hc, int dil){
  int i = blockIdx.x*256 + threadIdx.x;   // over NTOK*DIM
  int d = i & (DIM-1); int row = i >> 9; int t = row & (SEQ-1);
  float acc = cb[d];
  #pragma unroll
  for (int m=0;m<KSZ;m++){
    if (t - m*dil >= 0) acc += cwT[m*DIM + d] * (float)h1[i - m*dil*DIM];
  }
  float s = acc * sigm(acc);
  hc[i] = (f16)s;
}

// ---------------- unified tiled MFMA GEMM, T3 2-phase + global_load_lds ----------------
// C[M,N] = A[M,K] . B[N,K]^T, f16 operands, f32 accumulate. BN=64, 4 waves split M.
// EPI 0: dual (B0=W1,B1=W3): OH = f16(silu(c0)*c1), ld HIDN
// EPI 1: w2: val = c0 + XIN; OF = val; I += val (ld DIM)
// EPI 2: logits: OF = c0 (ld VOCAB); 1-D grid, XCD-striped (mstripe = bid&15)
template<int BM,int KD,int EPI>
__global__ __launch_bounds__(256) void k_mm(
    const f16* __restrict__ A, const f16* __restrict__ B0, const f16* __restrict__ B1,
    const float* __restrict__ XIN, float* __restrict__ OF, float* __restrict__ I,
    f16* __restrict__ OH){
  constexpr int WM = BM/4, MF = WM/16, NF = 4;
  constexpr int NMAT = (EPI==0) ? 2 : 1;
  constexpr int ATILE = BM*64;          // f16 elems per buffer
  constexpr int BTILE = NMAT*64*64;
  constexpr int STRIDE = ATILE + BTILE;
  constexpr int AI = (BM/4)/8;          // gload instrs per wave for A (8 rows each)
  constexpr int NT = KD/64;
  __shared__ f16 smem[2*STRIDE];
  int tid = threadIdx.x;
  int lane = tid & 63, wid = tid >> 6;
  int m0, n0;
  if constexpr (EPI==2){ int bid = blockIdx.x; m0 = (bid&15)*BM; n0 = (bid>>4)*64; }
  else { m0 = blockIdx.x*BM; n0 = blockIdx.y*64; }

  int lrow = lane >> 3, slot = lane & 7;   // staging decomposition

  // linear LDS dest + inverse-swizzled global source (rule #21):
  // LDS row r slot s holds global chunk s^(r&7); ds_read uses slot c^(r&7).
  auto stage = [&](int buf, int k0){
    f16* sA = smem + buf*STRIDE;
    f16* sB = sA + ATILE;
    #pragma unroll
    for (int j=0;j<AI;j++){
      int rowb = wid*(BM/4) + j*8;
      int row = rowb + lrow;
      gld16(A + (size_t)(m0+row)*KD + k0 + ((slot^(row&7))*8), sA + rowb*64);
    }
    #pragma unroll
    for (int j=0;j<2;j++){
      int rowb = wid*16 + j*8;
      int row = rowb + lrow;
      gld16(B0 + (size_t)(n0+row)*KD + k0 + ((slot^(row&7))*8), sB + rowb*64);
      if constexpr (EPI==0)
        gld16(B1 + (size_t)(n0+row)*KD + k0 + ((slot^(row&7))*8), sB + 4096 + rowb*64);
    }
  };

  f32x4 acc0[MF][NF] = {};
  f32x4 acc1[(EPI==0)?MF:1][(EPI==0)?NF:1] = {};

  stage(0, 0);
  __syncthreads();                       // drain prologue loads
  for (int t=0;t<NT;t++){
    int cur = t & 1;
    if (t+1 < NT) stage(cur^1, (t+1)*64);   // issue next tile BEFORE compute
    const f16* sA = smem + cur*STRIDE;
    const f16* sB = sA + ATILE;
    #pragma unroll
    for (int kk=0;kk<2;kk++){
      int kp0 = kk*4 + (lane>>4);        // 16B chunk index 0..7
      f16x8 af[MF], bf[NF], bg[(EPI==0)?NF:1];
      #pragma unroll
      for (int mf=0;mf<MF;mf++){
        int row = wid*WM + mf*16 + (lane&15);
        af[mf] = *reinterpret_cast<const f16x8*>(&sA[row*64 + (kp0^(row&7))*8]);
      }
      #pragma unroll
      for (int nf=0;nf<NF;nf++){
        int row = nf*16 + (lane&15);
        bf[nf] = *reinterpret_cast<const f16x8*>(&sB[row*64 + (kp0^(row&7))*8]);
        if constexpr (EPI==0)
          bg[nf] = *reinterpret_cast<const f16x8*>(&sB[4096 + row*64 + (kp0^(row&7))*8]);
      }
      #pragma unroll
      for (int mf=0;mf<MF;mf++){
        #pragma unroll
        for (int nf=0;nf<NF;nf++){
          acc0[mf][nf] = MFMA16(af[mf], bf[nf], acc0[mf][nf]);
          if constexpr (EPI==0)
            acc1[mf][nf] = MFMA16(af[mf], bg[nf], acc1[mf][nf]);
        }
      }
    }
    __syncthreads();    // drains stage(t+1) vmcnt + protects buffer reuse
  }

  // ---- LDS-staged coalesced epilogue (wave-private staging, stride 68) ----
  float* stg = (float*)smem + wid*(16*68);
  int dr = (lane>>4)*4, dc = lane&15;
  #pragma unroll
  for (int mf=0;mf<MF;mf++){
    #pragma unroll
    for (int nf=0;nf<NF;nf++){
      #pragma unroll
      for (int q=0;q<4;q++){
        float v;
        if constexpr (EPI==0){
          float x1 = acc0[mf][nf][q];
          v = x1*sigm(x1)*acc1[mf][nf][q];
        } else v = acc0[mf][nf][q];
        stg[(dr+q)*68 + nf*16 + dc] = v;
      }
    }
    int gmb = m0 + wid*WM + mf*16;
    if constexpr (EPI==0){
      #pragma unroll
      for (int pass=0;pass<2;pass++){
        int r = pass*8 + (lane>>3);
        int c = 8*(lane&7);
        float4 lo = *reinterpret_cast<float4*>(&stg[r*68 + c]);
        float4 hi = *reinterpret_cast<float4*>(&stg[r*68 + c + 4]);
        f16x8 o;
        o[0]=(f16)lo.x; o[1]=(f16)lo.y; o[2]=(f16)lo.z; o[3]=(f16)lo.w;
        o[4]=(f16)hi.x; o[5]=(f16)hi.y; o[6]=(f16)hi.z; o[7]=(f16)hi.w;
        *reinterpret_cast<f16x8*>(&OH[(size_t)(gmb+r)*HIDN + n0 + c]) = o;
      }
    } else if constexpr (EPI==1){
      #pragma unroll
      for (int pass=0;pass<4;pass++){
        int r = pass*4 + (lane>>4);
        int c = 4*(lane&15);
        float4 v = *reinterpret_cast<float4*>(&stg[r*68 + c]);
        size_t o = (size_t)(gmb+r)*DIM + n0 + c;
        float4 x = *reinterpret_cast<const float4*>(&XIN[o]);
        v.x += x.x; v.y += x.y; v.z += x.z; v.w += x.w;
        *reinterpret_cast<float4*>(&OF[o]) = v;
        float4 iv = *reinterpret_cast<const float4*>(&I[o]);
        iv.x += v.x; iv.y += v.y; iv.z += v.z; iv.w += v.w;
        *reinterpret_cast<float4*>(&I[o]) = iv;
      }
    } else {
      #pragma unroll
      for (int pass=0;pass<4;pass++){
        int r = pass*4 + (lane>>4);
        int c = 4*(lane&15);
        float4 v = *reinterpret_cast<float4*>(&stg[r*68 + c]);
        *reinterpret_cast<float4*>(&OF[(size_t)(gmb+r)*VOCAB + n0 + c]) = v;
      }
    }
  }
}

// ---------------- mix: parallel scan, one wave per (b,d) column ----------------
__global__ __launch_bounds__(64) void k_mix(float* __restrict__ x){
  int col = blockIdx.x;                 // 0..BATCH*DIM-1
  int b = col >> 9, d = col & (DIM-1);
  int lane = threadIdx.x;
  long o = (long)b*SEQ*DIM + d + (long)lane*16*DIM;
  float v[16]; float s = 0.f;
  #pragma unroll
  for (int j=0;j<16;j++){ v[j] = x[o + (long)j*DIM]; s += v[j]; }
  float t = s;
  #pragma unroll
  for (int off=1; off<64; off<<=1){
    float u = __shfl_up(t, off, 64);
    if (lane >= off) t += u;
  }
  float run = t - s;   // exclusive prefix
  #pragma unroll
  for (int j=0;j<16;j++){
    run += v[j];
    int tt = lane*16 + j;
    x[o + (long)j*DIM] = v[j] + MIXW*run/(float)(tt+1);
  }
}

// ---------------- sgate (low-rank gate) ----------------
__global__ __launch_bounds__(256) void k_sgate(const float* __restrict__ xnew,
    const float* __restrict__ xold, const float* __restrict__ nw,
    const float* __restrict__ dw, const float* __restrict__ db,
    const float* __restrict__ uw, const float* __restrict__ ub,
    float* __restrict__ out){
  __shared__ float raw[DIM];
  __shared__ float xn[DIM];
  __shared__ float part[256];
  __shared__ float hb[RANK];
  int row = blockIdx.x, tid = threadIdx.x;
  long base = (long)row*DIM;
  float ss = 0.f;
  for (int d=tid; d<DIM; d+=256){ float v = xnew[base+d]; raw[d]=v; ss += v*v; }
  ss = wred(ss);
  if ((tid&63)==0) part[tid>>6] = ss;
  __syncthreads();
  float tot = part[0]+part[1]+part[2]+part[3];
  float rs = rsqrtf(tot*(1.f/DIM)+1e-6f);
  for (int d=tid; d<DIM; d+=256) xn[d] = raw[d]*rs*nw[d];
  __syncthreads();
  int rr = tid & 63, q = tid >> 6;
  float p = 0.f;
  const float* dwr = dw + (long)rr*DIM + q*128;
  const float* xq = xn + q*128;
  #pragma unroll 8
  for (int d=0; d<128; d+=4){
    float4 wv = *reinterpret_cast<const float4*>(dwr+d);
    p += xq[d]*wv.x + xq[d+1]*wv.y + xq[d+2]*wv.z + xq[d+3]*wv.w;
  }
  part[tid] = p;
  __syncthreads();
  if (tid < RANK){
    float h = part[tid] + part[64+tid] + part[128+tid] + part[192+tid] + db[tid];
    hb[tid] = h * sigm(h);
  }
  __syncthreads();
  for (int d=tid; d<DIM; d+=256){
    float a = ub[d];
    const float* ur = uw + (long)d*RANK;
    #pragma unroll
    for (int rj=0;rj<RANK;rj+=4){
      float4 uv = *reinterpret_cast<const float4*>(ur+rj);
      a += hb[rj]*uv.x + hb[rj+1]*uv.y + hb[rj+2]*uv.z + hb[rj+3]*uv.w;
    }
    float g = sigm(a);
    out[base+d] = g*raw[d] + (1.f-g)*xold[base+d];
  }
}

// ---------------- host orchestration ----------------
extern "C" void kernel_launch(void* const* d_in, const int* in_sizes, int n_in,
                              void* d_out, int out_size, void* d_ws, size_t ws_size,
                              hipStream_t stream){
  const int*   idx           = (const int*)d_in[0];
  const float* emb           = (const float*)d_in[1];
  const float* pos           = (const float*)d_in[2];
  const float* emb_norm_w    = (const float*)d_in[3];
  const float* token_shift   = (const float*)d_in[4];
  const float* mem_gate_w    = (const float*)d_in[5];
  const float* mem_gate_b    = (const float*)d_in[6];
  const float* memory_p      = (const float*)d_in[7];
  const float* sg_norm       = (const float*)d_in[8];
  const float* sg_down_w     = (const float*)d_in[9];
  const float* sg_down_b     = (const float*)d_in[10];
  const float* sg_up_w       = (const float*)d_in[11];
  const float* sg_up_b       = (const float*)d_in[12];
  const float* final_norm_w  = (const float*)d_in[13];
  struct StackP { const float *nw, *cw, *cb, *w1, *w2, *w3, *kp, *ki, *gn; };
  StackP up { (const float*)d_in[14], (const float*)d_in[15], (const float*)d_in[16],
              (const float*)d_in[17], (const float*)d_in[18], (const float*)d_in[19],
              (const float*)d_in[20], (const float*)d_in[21], (const float*)d_in[23] };
  StackP dn { (const float*)d_in[24], (const float*)d_in[25], (const float*)d_in[26],
              (const float*)d_in[27], (const float*)d_in[28], (const float*)d_in[29],
              (const float*)d_in[30], (const float*)d_in[31], (const float*)d_in[33] };

  char* wp = (char*)d_ws;
  auto alloc = [&](size_t bytes)->void*{
    void* p = (void*)wp; wp += (bytes + 255) & ~(size_t)255; return p;
  };
  float* A0  = (float*)alloc((size_t)NTOK*DIM*4);
  float* A1  = (float*)alloc((size_t)NTOK*DIM*4);
  float* Cb  = (float*)alloc((size_t)NTOK*DIM*4);
  float* Ib  = (float*)alloc((size_t)NTOK*DIM*4);
  float* XIN = (float*)alloc((size_t)NTOK*DIM*4);
  f16*   H1  = (f16*)alloc((size_t)NTOK*DIM*2);
  f16*   HC  = (f16*)alloc((size_t)NTOK*DIM*2);
  f16*   G   = (f16*)alloc((size_t)NTOK*HIDN*2);
  const size_t WSZ = (size_t)NLAYERS*HIDN*DIM;   // per weight family per stack
  f16*   UpW1 = (f16*)alloc(WSZ*2);
  f16*   UpW2 = (f16*)alloc(WSZ*2);
  f16*   UpW3 = (f16*)alloc(WSZ*2);
  f16*   DnW1 = (f16*)alloc(WSZ*2);
  f16*   DnW2 = (f16*)alloc(WSZ*2);
  f16*   DnW3 = (f16*)alloc(WSZ*2);
  f16*   Ef   = (f16*)alloc((size_t)VOCAB*DIM*2);
  float* UpCT = (float*)alloc((size_t)NLAYERS*KSZ*DIM*4);
  float* DnCT = (float*)alloc((size_t)NLAYERS*KSZ*DIM*4);
  float* MEM  = (float*)alloc((size_t)BATCH*DIM*4);

  static const int updil[NLAYERS] = {1,2,4,8,16,32};
  static const int dndil[NLAYERS] = {32,16,8,4,2,1};

  // one-time weight conversions
  {
    long n4 = WSZ/4;
    int g = (int)((n4 + 255)/256);
    k_cvt<<<g,256,0,stream>>>(up.w1, UpW1, n4);
    k_cvt<<<g,256,0,stream>>>(up.w2, UpW2, n4);
    k_cvt<<<g,256,0,stream>>>(up.w3, UpW3, n4);
    k_cvt<<<g,256,0,stream>>>(dn.w1, DnW1, n4);
    k_cvt<<<g,256,0,stream>>>(dn.w2, DnW2, n4);
    k_cvt<<<g,256,0,stream>>>(dn.w3, DnW3, n4);
    long e4 = (long)VOCAB*DIM/4;
    k_cvt<<<(int)((e4+255)/256),256,0,stream>>>(emb, Ef, e4);
    int nc = NLAYERS*KSZ*DIM;
    k_cvtconv<<<(nc+255)/256,256,0,stream>>>(up.cw, UpCT, nc);
    k_cvtconv<<<(nc+255)/256,256,0,stream>>>(dn.cw, DnCT, nc);
  }

  k_embnorm<<<NTOK,64,0,stream>>>(idx, emb, pos, emb_norm_w, Cb);
  k_mem<<<(BATCH*DIM+255)/256,256,0,stream>>>(memory_p, mem_gate_w, mem_gate_b, MEM);
  k_shift<<<NTOK*DIM/256,256,0,stream>>>(Cb, MEM, token_shift, A0);

  auto run_stack = [&](const float* xs, const StackP& S, const float* CT,
                       const f16* W1f, const f16* W2f, const f16* W3f, const int* dil){
    hipMemcpyAsync(Ib, xs, (size_t)NTOK*DIM*4, hipMemcpyDeviceToDevice, stream);
    for (int l=0;l<NLAYERS;l++){
      const float* bin;
      if (l==0){
        bin = xs;
        k_rms<<<NTOK,64,0,stream>>>(xs, S.nw + l*DIM, H1);
      } else {
        k_pid<<<NTOK,64,0,stream>>>(Cb, Ib, 1.f/(float)l,
            S.kp+(l-1)*DIM, S.ki+(l-1)*DIM, S.gn+(l-1)*DIM, S.nw+l*DIM, XIN, H1);
        bin = XIN;
      }
      k_conv<<<NTOK*DIM/256,256,0,stream>>>(H1, CT + (size_t)l*KSZ*DIM, S.cb + l*DIM, HC, dil[l]);
      k_mm<128,512,0><<<dim3(NTOK/128, HIDN/64),256,0,stream>>>(
          HC, W1f + (size_t)l*HIDN*DIM, W3f + (size_t)l*HIDN*DIM,
          nullptr, nullptr, nullptr, G);
      k_mm<64,1024,1><<<dim3(NTOK/64, DIM/64),256,0,stream>>>(
          G, W2f + (size_t)l*DIM*HIDN, nullptr,
          bin, Cb, Ib, nullptr);
    }
  };

  // stack 1 (up)
  run_stack(A0, up, UpCT, UpW1, UpW2, UpW3, updil);
  k_mix<<<BATCH*DIM,64,0,stream>>>(Cb);
  k_sgate<<<NTOK,256,0,stream>>>(Cb, A0, sg_norm, sg_down_w, sg_down_b, sg_up_w, sg_up_b, A1);
  // stack 2 (down)
  run_stack(A1, dn, DnCT, DnW1, DnW2, DnW3, dndil);
  k_mix<<<BATCH*DIM,64,0,stream>>>(Cb);
  k_sgate<<<NTOK,256,0,stream>>>(Cb, A0, sg_norm+DIM, sg_down_w+RANK*DIM, sg_down_b+RANK,
                                 sg_up_w+DIM*RANK, sg_up_b+DIM, A1);
  // stack 3 (up again)
  run_stack(A1, up, UpCT, UpW1, UpW2, UpW3, updil);
  k_mix<<<BATCH*DIM,64,0,stream>>>(Cb);
  k_sgate<<<NTOK,256,0,stream>>>(Cb, A1, sg_norm+2*DIM, sg_down_w+2*RANK*DIM, sg_down_b+2*RANK,
                                 sg_up_w+2*DIM*RANK, sg_up_b+2*DIM, Cb);
  // final norm + logits (XCD-striped 1-D grid: bid&15 = m-stripe)
  k_rms<<<NTOK,64,0,stream>>>(Cb, final_norm_w, H1);
  k_mm<128,512,2><<<16*(VOCAB/64),256,0,stream>>>(
      H1, Ef, nullptr, nullptr, (float*)d_out, nullptr, nullptr);
}